// Round 1
// baseline (290.593 us; speedup 1.0000x reference)
//
#include <hip/hip_runtime.h>
#include <hip/hip_bf16.h>

#define B_ 2
#define S_ 2048
#define H_ 16
#define D_ 128
#define QBLK 64
#define KVBLK 64
#define NQB (S_/QBLK)
#define BH_ (B_*H_)

typedef __attribute__((ext_vector_type(4))) float f32x4;
typedef __attribute__((ext_vector_type(8))) short bf16x8;
typedef __attribute__((ext_vector_type(4))) unsigned short u16x4;
typedef __attribute__((ext_vector_type(8))) unsigned short u16x8;

static __device__ __forceinline__ unsigned short f2bf(float x){
  unsigned u = __builtin_bit_cast(unsigned, x);
  u += 0x7fffu + ((u >> 16) & 1u);
  return (unsigned short)(u >> 16);
}
static __device__ __forceinline__ float bf2f(unsigned short s){
  unsigned u = ((unsigned)s) << 16;
  return __builtin_bit_cast(float, u);
}

// ---------- pre-pass 1: K -> bf16 hi/lo (same [b][s][h][d] layout) ----------
__global__ __launch_bounds__(256) void cvt_split_kernel(
    const float* __restrict__ src, unsigned short* __restrict__ hi, unsigned short* __restrict__ lo)
{
  int idx = blockIdx.x * 256 + threadIdx.x;   // float4 index; grid is exact
  f32x4 v = reinterpret_cast<const f32x4*>(src)[idx];
  u16x4 h, l;
#pragma unroll
  for (int j = 0; j < 4; ++j){
    unsigned short hh = f2bf(v[j]);
    h[j] = hh;
    l[j] = f2bf(v[j] - bf2f(hh));
  }
  reinterpret_cast<u16x4*>(hi)[idx] = h;
  reinterpret_cast<u16x4*>(lo)[idx] = l;
}

// ---------- pre-pass 2: V -> V^T bf16 hi/lo, layout [bh][d][s] ----------
__global__ __launch_bounds__(256) void vt_kernel(
    const float* __restrict__ v, unsigned short* __restrict__ vthi, unsigned short* __restrict__ vtlo)
{
  __shared__ __align__(16) unsigned short thi[D_*72];  // [d][s_local], pad 64->72 (16B-multiple rows)
  __shared__ __align__(16) unsigned short tlo[D_*72];
  int bx = blockIdx.x;
  int bh = bx >> 5;        // 0..31
  int st = bx & 31;        // s-chunk of 64
  int b = bh >> 4, h = bh & 15;
  int s0 = st * 64;
  int t = threadIdx.x;
#pragma unroll
  for (int i = 0; i < 8; ++i){
    int idx = t + i*256;     // 0..2047
    int sl = idx >> 5;       // 0..63
    int d4 = idx & 31;       // float4 within row
    f32x4 val = *reinterpret_cast<const f32x4*>(v + ((size_t)((b*S_ + s0 + sl)*H_ + h))*D_ + d4*4);
#pragma unroll
    for (int j = 0; j < 4; ++j){
      int d = d4*4 + j;
      unsigned short hh = f2bf(val[j]);
      thi[d*72 + sl] = hh;
      tlo[d*72 + sl] = f2bf(val[j] - bf2f(hh));
    }
  }
  __syncthreads();
#pragma unroll
  for (int i = 0; i < 4; ++i){
    int idx = t + i*256;     // 0..1023
    int d = idx >> 3;        // 0..127
    int s8 = idx & 7;
    u16x8 hv = *reinterpret_cast<const u16x8*>(&thi[d*72 + s8*8]);
    u16x8 lv = *reinterpret_cast<const u16x8*>(&tlo[d*72 + s8*8]);
    size_t o = ((size_t)(bh*D_ + d))*S_ + s0 + s8*8;
    *reinterpret_cast<u16x8*>(vthi + o) = hv;
    *reinterpret_cast<u16x8*>(vtlo + o) = lv;
  }
}

// ---------- main: flash attention, hi/lo-split bf16 MFMA ----------
// Block: 256 thr = 4 waves; wave w owns q-rows [qb*64 + w*16, +16).
// LDS K tiles: [64 rows][128 d] bf16, 256B rows, 16B-slot XOR swizzle (slot ^ (row&7))
// LDS V^T tiles: [128 d][64 k] bf16, 128B rows, same swizzle.
// Swizzle applied on the global SOURCE of global_load_lds (linear LDS dest) + on reads.
__global__ __launch_bounds__(256,2) void attn_kernel(
    const float* __restrict__ q,
    const unsigned short* __restrict__ khi, const unsigned short* __restrict__ klo,
    const unsigned short* __restrict__ vthi, const unsigned short* __restrict__ vtlo,
    const float* __restrict__ scale_p, float* __restrict__ out)
{
  __shared__ __align__(16) unsigned short lkhi[KVBLK*D_];
  __shared__ __align__(16) unsigned short lklo[KVBLK*D_];
  __shared__ __align__(16) unsigned short lvhi[D_*KVBLK];
  __shared__ __align__(16) unsigned short lvlo[D_*KVBLK];
  __shared__ __align__(16) unsigned short lp[4][2][16*KVBLK];  // per-wave P hi/lo

  const int blk = blockIdx.x;
  const int bh = blk & (BH_-1);
  const int qb = (NQB-1) - (blk >> 5);   // heavy (large-qb) blocks dispatch first
  const int b = bh >> 4, h = bh & 15;
  const int tid = threadIdx.x;
  const int w = tid >> 6;
  const int lane = tid & 63;
  const int l15 = lane & 15;
  const int lhi = lane >> 4;

  const float qscale = scale_p[0] * 1.44269504088896340736f;  // fold log2(e) -> exp2 softmax

  // Q fragments (scaled), bf16 hi/lo, held in registers for the whole loop
  bf16x8 qh[4], ql[4];
  {
    const int qrow_g = qb*QBLK + w*16 + l15;
    const float* qrow = q + ((size_t)((b*S_ + qrow_g)*H_ + h))*D_;
#pragma unroll
    for (int c = 0; c < 4; ++c){
      int d0 = c*32 + lhi*8;
      f32x4 x0 = *reinterpret_cast<const f32x4*>(qrow + d0);
      f32x4 x1 = *reinterpret_cast<const f32x4*>(qrow + d0 + 4);
#pragma unroll
      for (int j = 0; j < 8; ++j){
        float x = (j < 4 ? x0[j] : x1[j-4]) * qscale;
        unsigned short hh = f2bf(x);
        qh[c][j] = (short)hh;
        ql[c][j] = (short)f2bf(x - bf2f(hh));
      }
    }
  }

  const f32x4 zero4 = {0.f, 0.f, 0.f, 0.f};
  f32x4 o[8];
#pragma unroll
  for (int i = 0; i < 8; ++i) o[i] = zero4;
  float m[4]    = {-1e30f,-1e30f,-1e30f,-1e30f};
  float lsum[4] = {0.f,0.f,0.f,0.f};

  // staging role per wave: w0->K_hi, w1->K_lo, w2->VT_hi, w3->VT_lo (16KB each, 16x 1KB instrs)
  const bool isK = (w < 2);
  const unsigned short* gtab = (w==0) ? khi : (w==1) ? klo : (w==2) ? vthi : vtlo;
  unsigned short* larr = (w==0) ? lkhi : (w==1) ? lklo : (w==2) ? lvhi : lvlo;

  for (int kt = 0; kt <= qb; ++kt){
    __syncthreads();   // prior tile fully consumed before overwrite
    if (isK){
#pragma unroll
      for (int i = 0; i < 16; ++i){
        int r = 4*i + lhi;                 // K row within tile
        int slot = l15 ^ (r & 7);          // pre-swizzled 16B slot (inverse == forward)
        const unsigned short* gp = gtab + ((size_t)((b*S_ + kt*KVBLK + r)*H_ + h))*D_ + slot*8;
        __builtin_amdgcn_global_load_lds((const __attribute__((address_space(1))) void*)gp,
                                         (__attribute__((address_space(3))) void*)(larr + i*512),
                                         16, 0, 0);
      }
    } else {
#pragma unroll
      for (int i = 0; i < 16; ++i){
        int d = 8*i + (lane >> 3);         // VT row (d)
        int slot = (lane & 7) ^ (d & 7);
        const unsigned short* gp = gtab + ((size_t)(bh*D_ + d))*S_ + kt*KVBLK + slot*8;
        __builtin_amdgcn_global_load_lds((const __attribute__((address_space(1))) void*)gp,
                                         (__attribute__((address_space(3))) void*)(larr + i*512),
                                         16, 0, 0);
      }
    }
    __syncthreads();   // compiler drains vmcnt before barrier -> tile visible

    // ---- QK^T: S = Qh*Kh + Ql*Kh + Qh*Kl (drop lo*lo) ----
    f32x4 sc[4];
#pragma unroll
    for (int nt = 0; nt < 4; ++nt) sc[nt] = zero4;
#pragma unroll
    for (int c = 0; c < 4; ++c){
      int d0 = c*32 + lhi*8;
      bf16x8 kh[4], kl[4];
#pragma unroll
      for (int nt = 0; nt < 4; ++nt){
        int kr = nt*16 + l15;
        int idx = kr*D_ + (d0 ^ ((kr & 7) << 3));   // swizzled read
        kh[nt] = *reinterpret_cast<const bf16x8*>(&lkhi[idx]);
        kl[nt] = *reinterpret_cast<const bf16x8*>(&lklo[idx]);
      }
#pragma unroll
      for (int nt = 0; nt < 4; ++nt){
        sc[nt] = __builtin_amdgcn_mfma_f32_16x16x32_bf16(qh[c], kh[nt], sc[nt], 0, 0, 0);
        sc[nt] = __builtin_amdgcn_mfma_f32_16x16x32_bf16(ql[c], kh[nt], sc[nt], 0, 0, 0);
        sc[nt] = __builtin_amdgcn_mfma_f32_16x16x32_bf16(qh[c], kl[nt], sc[nt], 0, 0, 0);
      }
    }

    // causal mask on the diagonal tile
    if (kt == qb){
#pragma unroll
      for (int nt = 0; nt < 4; ++nt){
        int coll = nt*16 + l15;
#pragma unroll
        for (int r = 0; r < 4; ++r){
          int rowl = w*16 + lhi*4 + r;
          if (coll > rowl) sc[nt][r] = -1e30f;
        }
      }
    }

    // ---- online softmax (rows live on 16-lane col groups; butterfly over l15) ----
    float corr[4];
#pragma unroll
    for (int r = 0; r < 4; ++r){
      float t = fmaxf(fmaxf(sc[0][r], sc[1][r]), fmaxf(sc[2][r], sc[3][r]));
      t = fmaxf(t, __shfl_xor(t, 1));
      t = fmaxf(t, __shfl_xor(t, 2));
      t = fmaxf(t, __shfl_xor(t, 4));
      t = fmaxf(t, __shfl_xor(t, 8));
      float mn = fmaxf(m[r], t);
      corr[r] = exp2f(m[r] - mn);
      m[r] = mn;
    }
#pragma unroll
    for (int r = 0; r < 4; ++r){
      float rs = 0.f;
#pragma unroll
      for (int nt = 0; nt < 4; ++nt){
        float p = exp2f(sc[nt][r] - m[r]);
        sc[nt][r] = p;
        rs += p;
      }
      rs += __shfl_xor(rs, 1);
      rs += __shfl_xor(rs, 2);
      rs += __shfl_xor(rs, 4);
      rs += __shfl_xor(rs, 8);
      lsum[r] = lsum[r]*corr[r] + rs;
    }
#pragma unroll
    for (int i = 0; i < 8; ++i){
#pragma unroll
      for (int r = 0; r < 4; ++r) o[i][r] *= corr[r];
    }

    // ---- P -> per-wave LDS (bf16 hi/lo, swizzled rows of 128B) ----
#pragma unroll
    for (int nt = 0; nt < 4; ++nt){
      int col = nt*16 + l15;
#pragma unroll
      for (int r = 0; r < 4; ++r){
        int row = lhi*4 + r;
        int idx = row*64 + (col ^ ((row & 7) << 3));
        float p = sc[nt][r];
        unsigned short hh = f2bf(p);
        lp[w][0][idx] = hh;
        lp[w][1][idx] = f2bf(p - bf2f(hh));
      }
    }

    // ---- P·V: O += Ph*Vh + Pl*Vh + Ph*Vl ----
#pragma unroll
    for (int c2 = 0; c2 < 2; ++c2){
      int k0 = c2*32 + lhi*8;
      int pidx = l15*64 + (k0 ^ ((l15 & 7) << 3));
      bf16x8 pah = *reinterpret_cast<const bf16x8*>(&lp[w][0][pidx]);
      bf16x8 pal = *reinterpret_cast<const bf16x8*>(&lp[w][1][pidx]);
#pragma unroll
      for (int nt = 0; nt < 8; ++nt){
        int dr = nt*16 + l15;
        int vidx = dr*64 + (k0 ^ ((dr & 7) << 3));
        bf16x8 vbh = *reinterpret_cast<const bf16x8*>(&lvhi[vidx]);
        bf16x8 vbl = *reinterpret_cast<const bf16x8*>(&lvlo[vidx]);
        o[nt] = __builtin_amdgcn_mfma_f32_16x16x32_bf16(pah, vbh, o[nt], 0, 0, 0);
        o[nt] = __builtin_amdgcn_mfma_f32_16x16x32_bf16(pal, vbh, o[nt], 0, 0, 0);
        o[nt] = __builtin_amdgcn_mfma_f32_16x16x32_bf16(pah, vbl, o[nt], 0, 0, 0);
      }
    }
  }

  // ---- epilogue: normalize and store fp32 ----
  float inv[4];
#pragma unroll
  for (int r = 0; r < 4; ++r) inv[r] = 1.0f / lsum[r];
#pragma unroll
  for (int nt = 0; nt < 8; ++nt){
    int d = nt*16 + l15;
#pragma unroll
    for (int r = 0; r < 4; ++r){
      int sq = qb*QBLK + w*16 + lhi*4 + r;
      out[((size_t)((b*S_ + sq)*H_ + h))*D_ + d] = o[nt][r] * inv[r];
    }
  }
}

extern "C" void kernel_launch(void* const* d_in, const int* in_sizes, int n_in,
                              void* d_out, int out_size, void* d_ws, size_t ws_size,
                              hipStream_t stream)
{
  const float* q     = (const float*)d_in[0];
  const float* k     = (const float*)d_in[1];
  const float* v     = (const float*)d_in[2];
  const float* scale = (const float*)d_in[4];   // d_in[3] = attention_mask (all ones, unused)
  float* out = (float*)d_out;
  (void)in_sizes; (void)n_in; (void)out_size; (void)ws_size;

  const size_t N = (size_t)B_ * S_ * H_ * D_;   // 8388608 elements
  // workspace: 4 bf16 arrays = 64 MiB total
  unsigned short* khi  = (unsigned short*)d_ws;
  unsigned short* klo  = khi + N;
  unsigned short* vthi = klo + N;
  unsigned short* vtlo = vthi + N;

  cvt_split_kernel<<<(int)(N/4/256), 256, 0, stream>>>(k, khi, klo);
  vt_kernel<<<BH_*(S_/64), 256, 0, stream>>>(v, vthi, vtlo);
  attn_kernel<<<BH_*NQB, 256, 0, stream>>>(q, khi, klo, vthi, vtlo, scale, out);
}

// Round 2
// 258.931 us; speedup vs baseline: 1.1223x; 1.1223x over previous
//
#include <hip/hip_runtime.h>
#include <hip/hip_bf16.h>

#define B_ 2
#define S_ 2048
#define H_ 16
#define D_ 128
#define QBLK 64
#define KVB 32
#define NQB (S_/QBLK)
#define BH_ (B_*H_)

typedef __attribute__((ext_vector_type(4))) float f32x4;
typedef __attribute__((ext_vector_type(8))) short bf16x8;
typedef __attribute__((ext_vector_type(8))) unsigned short u16x8;

static __device__ __forceinline__ unsigned short f2bf(float x){
  unsigned u = __builtin_bit_cast(unsigned, x);
  u += 0x7fffu + ((u >> 16) & 1u);
  return (unsigned short)(u >> 16);
}
static __device__ __forceinline__ float bf2f(unsigned short s){
  unsigned u = ((unsigned)s) << 16;
  return __builtin_bit_cast(float, u);
}

// ---------- pre-pass 1: K -> bf16 (same [b][s][h][d] layout) ----------
__global__ __launch_bounds__(256) void cvt_kernel(
    const float* __restrict__ src, unsigned short* __restrict__ hi)
{
  int idx = blockIdx.x * 256 + threadIdx.x;   // u16x8 chunk index; grid exact
  f32x4 a = reinterpret_cast<const f32x4*>(src)[idx*2];
  f32x4 c = reinterpret_cast<const f32x4*>(src)[idx*2+1];
  u16x8 h;
#pragma unroll
  for (int j = 0; j < 4; ++j){ h[j] = f2bf(a[j]); h[4+j] = f2bf(c[j]); }
  reinterpret_cast<u16x8*>(hi)[idx] = h;
}

// ---------- pre-pass 2: V -> V^T bf16, layout [bh][d][s] ----------
__global__ __launch_bounds__(256) void vt_kernel(
    const float* __restrict__ v, unsigned short* __restrict__ vthi)
{
  __shared__ __align__(16) unsigned short thi[D_*72];  // [d][s_local], pad 64->72
  int bx = blockIdx.x;
  int bh = bx >> 5;        // 0..31
  int st = bx & 31;        // s-chunk of 64
  int b = bh >> 4, h = bh & 15;
  int s0 = st * 64;
  int t = threadIdx.x;
#pragma unroll
  for (int i = 0; i < 8; ++i){
    int idx = t + i*256;     // 0..2047
    int sl = idx >> 5;       // 0..63
    int d4 = idx & 31;       // float4 within row
    f32x4 val = *reinterpret_cast<const f32x4*>(v + ((size_t)((b*S_ + s0 + sl)*H_ + h))*D_ + d4*4);
#pragma unroll
    for (int j = 0; j < 4; ++j) thi[(d4*4+j)*72 + sl] = f2bf(val[j]);
  }
  __syncthreads();
#pragma unroll
  for (int i = 0; i < 4; ++i){
    int idx = t + i*256;     // 0..1023
    int d = idx >> 3;        // 0..127
    int s8 = idx & 7;
    u16x8 hv = *reinterpret_cast<const u16x8*>(&thi[d*72 + s8*8]);
    *reinterpret_cast<u16x8*>(vthi + ((size_t)(bh*D_ + d))*S_ + s0 + s8*8) = hv;
  }
}

// ---------- main: flash attention, 2-term bf16 MFMA, 2-phase pipeline ----------
// 256 thr = 4 waves; wave w owns q-rows [qb*64 + w*16, +16). KV tiles of 32, dbuf.
// K tile [32][128] bf16 (256B rows), 16B-slot swizzle: slot ^= (row&7)
// V^T tile [128][32] bf16 (64B rows), slot ^= (row&3)
// P tile per-wave [16][32] hi/lo, slot ^= ((row>>2)&3)
// Swizzle realized as: linear LDS dest for global_load_lds + inverse-swizzled
// global SOURCE chunk + swizzled read (rule: both-sides-or-neither, involution).
__global__ __launch_bounds__(256,3) void attn_kernel(
    const float* __restrict__ q,
    const unsigned short* __restrict__ khi,
    const unsigned short* __restrict__ vthi,
    const float* __restrict__ scale_p, float* __restrict__ out)
{
  __shared__ __align__(16) unsigned short lk[2][KVB*D_];    // 8KB x2
  __shared__ __align__(16) unsigned short lv[2][D_*KVB];    // 8KB x2
  __shared__ __align__(16) unsigned short lp[4][2][16*KVB]; // 1KB x8

  const int blk = blockIdx.x;
  const int bh = blk & (BH_-1);
  // CU-balanced qb map: resident sets {g, g+8, g+16, g+24} sum to 62 tiles
  const int g = blk >> 5;
  const int gg = g & 7, q4 = g >> 3;
  const int qb = (q4==0) ? 31-gg : (q4==1) ? gg : (q4==2) ? 23-gg : 8+gg;
  const int b = bh >> 4, h = bh & 15;
  const int tid = threadIdx.x;
  const int w = tid >> 6;
  const int lane = tid & 63;
  const int l15 = lane & 15;
  const int lhi = lane >> 4;

  const float qscale = scale_p[0] * 1.44269504088896340736f;  // fold log2(e)

  // Q fragments (scaled), bf16 hi/lo, registers for whole loop
  bf16x8 qh[4], ql[4];
  {
    const int qrow_g = qb*QBLK + w*16 + l15;
    const float* qrow = q + ((size_t)((b*S_ + qrow_g)*H_ + h))*D_;
#pragma unroll
    for (int c = 0; c < 4; ++c){
      int d0 = c*32 + lhi*8;
      f32x4 x0 = *reinterpret_cast<const f32x4*>(qrow + d0);
      f32x4 x1 = *reinterpret_cast<const f32x4*>(qrow + d0 + 4);
#pragma unroll
      for (int j = 0; j < 8; ++j){
        float x = (j < 4 ? x0[j] : x1[j-4]) * qscale;
        unsigned short hh = f2bf(x);
        qh[c][j] = (short)hh;
        ql[c][j] = (short)f2bf(x - bf2f(hh));
      }
    }
  }

  const f32x4 zero4 = {0.f,0.f,0.f,0.f};
  f32x4 o[8];
#pragma unroll
  for (int i = 0; i < 8; ++i) o[i] = zero4;
  float m[4]    = {-1e30f,-1e30f,-1e30f,-1e30f};
  float lsum[4] = {0.f,0.f,0.f,0.f};

  // stage one 32-wide KV tile into buffer `buf` (4 gload_lds per wave)
  auto stage = [&](int buf, int kt){
    if (w < 2){
#pragma unroll
      for (int j = 0; j < 4; ++j){
        int i = w*4 + j;                    // 0..7, 1KB each
        int r = i*4 + (lane >> 4);          // K row 0..31
        int s = lane & 15;                  // 16B slot
        const unsigned short* gp = khi + ((size_t)((b*S_ + kt*KVB + r)*H_ + h))*D_ + ((s ^ (r & 7))*8);
        __builtin_amdgcn_global_load_lds((const __attribute__((address_space(1))) void*)gp,
                                         (__attribute__((address_space(3))) void*)(&lk[buf][i*512]),
                                         16, 0, 0);
      }
    } else {
#pragma unroll
      for (int j = 0; j < 4; ++j){
        int i = (w-2)*4 + j;                // 0..7
        int d = i*16 + (lane >> 2);         // V^T row 0..127
        int s = lane & 3;
        const unsigned short* gp = vthi + ((size_t)(bh*D_ + d))*S_ + kt*KVB + ((s ^ (d & 3))*8);
        __builtin_amdgcn_global_load_lds((const __attribute__((address_space(1))) void*)gp,
                                         (__attribute__((address_space(3))) void*)(&lv[buf][i*512]),
                                         16, 0, 0);
      }
    }
  };

  const int NT = 2*qb + 2;
  stage(0, 0);
  __syncthreads();

  for (int kt = 0; kt < NT; ++kt){
    const int buf = kt & 1;
    if (kt + 1 < NT) stage(buf ^ 1, kt + 1);   // issue next tile; flies under compute

    // waves 0,1 are fully masked on the last diagonal sub-tile
    const bool active = !(kt == 2*qb + 1 && w < 2);
    if (active){
      // ---- QK^T (2-term) ----
      f32x4 sc[2] = {zero4, zero4};
#pragma unroll
      for (int c = 0; c < 4; ++c){
        bf16x8 kf[2];
#pragma unroll
        for (int nt = 0; nt < 2; ++nt){
          int kr = nt*16 + l15;
          int idx = kr*D_ + (((c*4 + lhi) ^ (kr & 7))*8);
          kf[nt] = *reinterpret_cast<const bf16x8*>(&lk[buf][idx]);
        }
#pragma unroll
        for (int nt = 0; nt < 2; ++nt){
          sc[nt] = __builtin_amdgcn_mfma_f32_16x16x32_bf16(qh[c], kf[nt], sc[nt], 0, 0, 0);
          sc[nt] = __builtin_amdgcn_mfma_f32_16x16x32_bf16(ql[c], kf[nt], sc[nt], 0, 0, 0);
        }
      }

      // causal mask (only the two diagonal sub-tiles need it)
      if (kt >= 2*qb){
#pragma unroll
        for (int nt = 0; nt < 2; ++nt){
          int col = kt*KVB + nt*16 + l15;
#pragma unroll
          for (int r = 0; r < 4; ++r){
            int row = qb*QBLK + w*16 + lhi*4 + r;
            if (col > row) sc[nt][r] = -1e30f;
          }
        }
      }

      // ---- online softmax (rows on 16-lane col groups) ----
      float corr[4];
#pragma unroll
      for (int r = 0; r < 4; ++r){
        float t = fmaxf(sc[0][r], sc[1][r]);
        t = fmaxf(t, __shfl_xor(t, 1));
        t = fmaxf(t, __shfl_xor(t, 2));
        t = fmaxf(t, __shfl_xor(t, 4));
        t = fmaxf(t, __shfl_xor(t, 8));
        float mn = fmaxf(m[r], t);
        corr[r] = exp2f(m[r] - mn);
        m[r] = mn;
      }
#pragma unroll
      for (int r = 0; r < 4; ++r){
        float rs = 0.f;
#pragma unroll
        for (int nt = 0; nt < 2; ++nt){
          float p = exp2f(sc[nt][r] - m[r]);
          sc[nt][r] = p;
          rs += p;
        }
        rs += __shfl_xor(rs, 1);
        rs += __shfl_xor(rs, 2);
        rs += __shfl_xor(rs, 4);
        rs += __shfl_xor(rs, 8);
        lsum[r] = lsum[r]*corr[r] + rs;
      }
#pragma unroll
      for (int i = 0; i < 8; ++i){
#pragma unroll
        for (int r = 0; r < 4; ++r) o[i][r] *= corr[r];
      }

      // ---- P -> per-wave LDS (hi/lo, swizzled) ----
#pragma unroll
      for (int nt = 0; nt < 2; ++nt){
        int col = nt*16 + l15;
#pragma unroll
        for (int r = 0; r < 4; ++r){
          int row = lhi*4 + r;
          int idx = row*KVB + (((col >> 3) ^ ((row >> 2) & 3))*8) + (col & 7);
          float p = sc[nt][r];
          unsigned short hh = f2bf(p);
          lp[w][0][idx] = hh;
          lp[w][1][idx] = f2bf(p - bf2f(hh));
        }
      }

      // ---- P·V (2-term) ----
      {
        int pidx = l15*KVB + ((lhi ^ ((l15 >> 2) & 3))*8);
        bf16x8 pah = *reinterpret_cast<const bf16x8*>(&lp[w][0][pidx]);
        bf16x8 pal = *reinterpret_cast<const bf16x8*>(&lp[w][1][pidx]);
#pragma unroll
        for (int nt = 0; nt < 8; ++nt){
          int dr = nt*16 + l15;
          int vidx = dr*KVB + ((lhi ^ (dr & 3))*8);
          bf16x8 vb = *reinterpret_cast<const bf16x8*>(&lv[buf][vidx]);
          o[nt] = __builtin_amdgcn_mfma_f32_16x16x32_bf16(pah, vb, o[nt], 0, 0, 0);
          o[nt] = __builtin_amdgcn_mfma_f32_16x16x32_bf16(pal, vb, o[nt], 0, 0, 0);
        }
      }
    }

    __syncthreads();   // drains just-issued stage loads; joins all waves
  }

  // ---- epilogue: normalize, store fp32 ----
  float inv[4];
#pragma unroll
  for (int r = 0; r < 4; ++r) inv[r] = 1.0f / lsum[r];
#pragma unroll
  for (int nt = 0; nt < 8; ++nt){
    int d = nt*16 + l15;
#pragma unroll
    for (int r = 0; r < 4; ++r){
      int sq = qb*QBLK + w*16 + lhi*4 + r;
      out[((size_t)((b*S_ + sq)*H_ + h))*D_ + d] = o[nt][r] * inv[r];
    }
  }
}

extern "C" void kernel_launch(void* const* d_in, const int* in_sizes, int n_in,
                              void* d_out, int out_size, void* d_ws, size_t ws_size,
                              hipStream_t stream)
{
  const float* q     = (const float*)d_in[0];
  const float* k     = (const float*)d_in[1];
  const float* v     = (const float*)d_in[2];
  const float* scale = (const float*)d_in[4];   // d_in[3] = attention_mask (unused)
  float* out = (float*)d_out;
  (void)in_sizes; (void)n_in; (void)out_size; (void)ws_size;

  const size_t N = (size_t)B_ * S_ * H_ * D_;   // 8388608
  unsigned short* khi  = (unsigned short*)d_ws;        // 16 MiB
  unsigned short* vthi = khi + N;                      // 16 MiB

  cvt_kernel<<<(int)(N/8/256), 256, 0, stream>>>(k, khi);
  vt_kernel<<<BH_*(S_/64), 256, 0, stream>>>(v, vthi);
  attn_kernel<<<BH_*NQB, 256, 0, stream>>>(q, khi, vthi, scale, out);
}

// Round 9
// 231.160 us; speedup vs baseline: 1.2571x; 1.1201x over previous
//
#include <hip/hip_runtime.h>
#include <hip/hip_bf16.h>

#define B_ 2
#define S_ 2048
#define H_ 16
#define D_ 128
#define QBLK 64
#define KVB 32
#define NQB (S_/QBLK)
#define BH_ (B_*H_)

typedef __attribute__((ext_vector_type(4))) float f32x4;
typedef __attribute__((ext_vector_type(8))) short bf16x8;
typedef __attribute__((ext_vector_type(4))) unsigned int u32x4;
typedef __attribute__((ext_vector_type(8))) unsigned short u16x8;

static __device__ __forceinline__ unsigned short f2bf(float x){
  unsigned u = __builtin_bit_cast(unsigned, x);
  u += 0x7fffu + ((u >> 16) & 1u);
  return (unsigned short)(u >> 16);
}
static __device__ __forceinline__ float bf2f(unsigned short s){
  unsigned u = ((unsigned)s) << 16;
  return __builtin_bit_cast(float, u);
}
// packed 2xf32 -> 2xbf16 in one u32 via HW v_cvt_pk_bf16_f32 (RNE; low16 = x).
// NOTE: no builtin on gfx950, and __hip_bfloat162 is not trivially copyable
// (bit_cast rejects it) -> inline asm per T12 recipe.
static __device__ __forceinline__ unsigned pkbf(float x, float y){
  unsigned r;
  asm("v_cvt_pk_bf16_f32 %0, %1, %2" : "=v"(r) : "v"(x), "v"(y));
  return r;
}
static __device__ __forceinline__ float asf(unsigned u){ return __builtin_bit_cast(float, u); }

// ---------- fused prepass: K -> bf16 (same layout) + V -> V^T bf16 [bh][d][s] ----------
// grid 1024 = 32 bh x 32 s-chunks of 64
__global__ __launch_bounds__(256) void prep_kernel(
    const float* __restrict__ k, const float* __restrict__ v,
    unsigned short* __restrict__ khi, unsigned short* __restrict__ vthi)
{
  __shared__ __align__(16) unsigned int tp[64*65];   // u32 (d-pair packed) [dp][sl], pad 65
  const int bx = blockIdx.x;
  const int bh = bx >> 5;
  const int st = bx & 31;
  const int b = bh >> 4, h = bh & 15;
  const int s0 = st * 64;
  const int t = threadIdx.x;

  // --- K convert: 64 rows x 128 d, coalesced 16B in / 16B out ---
#pragma unroll
  for (int i = 0; i < 4; ++i){
    int task = t + i*256;          // 0..1023
    int row = task >> 4;           // 0..63
    int c8 = task & 15;            // 8-elem chunk
    const float* kp = k + ((size_t)((b*S_ + s0 + row)*H_ + h))*D_ + c8*8;
    f32x4 a = *reinterpret_cast<const f32x4*>(kp);
    f32x4 c = *reinterpret_cast<const f32x4*>(kp + 4);
    u32x4 hv;
    hv[0] = pkbf(a[0], a[1]); hv[1] = pkbf(a[2], a[3]);
    hv[2] = pkbf(c[0], c[1]); hv[3] = pkbf(c[2], c[3]);
    *reinterpret_cast<u32x4*>(khi + ((size_t)((b*S_ + s0 + row)*H_ + h))*D_ + c8*8) = hv;
  }

  // --- V transpose phase 1: read f32x4, pack d-pairs into u32 tile (2-way banks = free) ---
#pragma unroll
  for (int i = 0; i < 8; ++i){
    int idx = t + i*256;           // 0..2047
    int sl = idx >> 5;             // 0..63
    int d4 = idx & 31;             // float4 chunk
    f32x4 val = *reinterpret_cast<const f32x4*>(v + ((size_t)((b*S_ + s0 + sl)*H_ + h))*D_ + d4*4);
    tp[(2*d4 + 0)*65 + sl] = pkbf(val[0], val[1]);
    tp[(2*d4 + 1)*65 + sl] = pkbf(val[2], val[3]);
  }
  __syncthreads();
  // --- phase 2: read 8 u32 (2 d-rows x 8 s), de-interleave, 16B stores ---
#pragma unroll
  for (int i = 0; i < 2; ++i){
    int task = t + i*256;          // 0..511
    int dp = task >> 3;            // 0..63
    int s8 = task & 7;
    unsigned u[8];
#pragma unroll
    for (int kk = 0; kk < 8; ++kk) u[kk] = tp[dp*65 + s8*8 + kk];
    u32x4 lo4, hi4;
#pragma unroll
    for (int k2 = 0; k2 < 4; ++k2){
      unsigned a = u[2*k2], bb = u[2*k2+1];
      lo4[k2] = (bb << 16) | (a & 0xffffu);
      hi4[k2] = (bb & 0xffff0000u) | (a >> 16);
    }
    size_t o0 = ((size_t)(bh*D_ + 2*dp))*S_ + s0 + s8*8;
    *reinterpret_cast<u32x4*>(vthi + o0)       = lo4;   // d = 2dp
    *reinterpret_cast<u32x4*>(vthi + o0 + S_)  = hi4;   // d = 2dp+1
  }
}

// ---------- main: flash attention, swapped QK^T, in-register softmax/P ----------
// 4 waves; wave w owns q-rows [qb*64 + w*16, +16). KVB=32 dbuf, 2-phase pipeline.
// K tile [32][128] bf16, 16B-slot swizzle slot^=(row&7); V^T tile [128][32], slot^=(row&3).
// Swapped QK: st = mfma(Kfrag, Qfrag) -> lane holds S[k=lhi*4+r+16nt][q=l15].
// P assembled into PV A-frags purely via xor16+xor32 shuffles (no LDS).
__global__ __launch_bounds__(256,3) void attn_kernel(
    const float* __restrict__ q,
    const unsigned short* __restrict__ khi,
    const unsigned short* __restrict__ vthi,
    const float* __restrict__ scale_p, float* __restrict__ out)
{
  __shared__ __align__(16) unsigned short lk[2][KVB*D_];    // 8KB x2
  __shared__ __align__(16) unsigned short lv[2][D_*KVB];    // 8KB x2

  const int blk = blockIdx.x;
  const int bh = blk & (BH_-1);
  const int g = blk >> 5;
  const int gg = g & 7, q4 = g >> 3;
  const int qb = (q4==0) ? 31-gg : (q4==1) ? gg : (q4==2) ? 23-gg : 8+gg;
  const int b = bh >> 4, h = bh & 15;
  const int tid = threadIdx.x;
  const int w = tid >> 6;
  const int lane = tid & 63;
  const int l15 = lane & 15;
  const int lhi = lane >> 4;

  const float qscale = scale_p[0] * 1.44269504088896340736f;  // fold log2(e)

  // Q fragments (scaled), bf16 hi/lo, registers for whole loop
  bf16x8 qh[4], ql[4];
  {
    const int qrow_g = qb*QBLK + w*16 + l15;
    const float* qrow = q + ((size_t)((b*S_ + qrow_g)*H_ + h))*D_;
#pragma unroll
    for (int c = 0; c < 4; ++c){
      int d0 = c*32 + lhi*8;
      f32x4 x0 = *reinterpret_cast<const f32x4*>(qrow + d0);
      f32x4 x1 = *reinterpret_cast<const f32x4*>(qrow + d0 + 4);
#pragma unroll
      for (int j = 0; j < 8; ++j){
        float x = (j < 4 ? x0[j] : x1[j-4]) * qscale;
        unsigned short hh = f2bf(x);
        qh[c][j] = (short)hh;
        ql[c][j] = (short)f2bf(x - bf2f(hh));
      }
    }
  }

  const f32x4 zero4 = {0.f,0.f,0.f,0.f};
  f32x4 o[8];
#pragma unroll
  for (int i = 0; i < 8; ++i) o[i] = zero4;
  float m = -1e30f;     // per-lane (q = l15), log2 units
  float lsum = 0.f;

  auto stage = [&](int buf, int kt){
    if (w < 2){
#pragma unroll
      for (int j = 0; j < 4; ++j){
        int i = w*4 + j;
        int r = i*4 + (lane >> 4);
        int s = lane & 15;
        const unsigned short* gp = khi + ((size_t)((b*S_ + kt*KVB + r)*H_ + h))*D_ + ((s ^ (r & 7))*8);
        __builtin_amdgcn_global_load_lds((const __attribute__((address_space(1))) void*)gp,
                                         (__attribute__((address_space(3))) void*)(&lk[buf][i*512]),
                                         16, 0, 0);
      }
    } else {
#pragma unroll
      for (int j = 0; j < 4; ++j){
        int i = (w-2)*4 + j;
        int d = i*16 + (lane >> 2);
        int s = lane & 3;
        const unsigned short* gp = vthi + ((size_t)(bh*D_ + d))*S_ + kt*KVB + ((s ^ (d & 3))*8);
        __builtin_amdgcn_global_load_lds((const __attribute__((address_space(1))) void*)gp,
                                         (__attribute__((address_space(3))) void*)(&lv[buf][i*512]),
                                         16, 0, 0);
      }
    }
  };

  const int NT = 2*qb + 2;
  stage(0, 0);
  __syncthreads();

  for (int kt = 0; kt < NT; ++kt){
    const int buf = kt & 1;
    if (kt + 1 < NT) stage(buf ^ 1, kt + 1);

    const bool active = !(kt == 2*qb + 1 && w < 2);
    if (active){
      // ---- swapped QK^T: st[nt] = S^T[k][q], 2-term (Qh+Ql)·Kh ----
      f32x4 st[2] = {zero4, zero4};
      __builtin_amdgcn_s_setprio(1);
#pragma unroll
      for (int c = 0; c < 4; ++c){
        bf16x8 kf[2];
#pragma unroll
        for (int nt = 0; nt < 2; ++nt){
          int kr = nt*16 + l15;
          int idx = kr*D_ + (((c*4 + lhi) ^ (kr & 7))*8);
          kf[nt] = *reinterpret_cast<const bf16x8*>(&lk[buf][idx]);
        }
#pragma unroll
        for (int nt = 0; nt < 2; ++nt){
          st[nt] = __builtin_amdgcn_mfma_f32_16x16x32_bf16(kf[nt], qh[c], st[nt], 0, 0, 0);
          st[nt] = __builtin_amdgcn_mfma_f32_16x16x32_bf16(kf[nt], ql[c], st[nt], 0, 0, 0);
        }
      }
      __builtin_amdgcn_s_setprio(0);

      // causal mask (diagonal tiles only): lane holds k = kt*32+nt*16+lhi*4+r, q = l15
      if (kt >= 2*qb){
        int qg = qb*QBLK + w*16 + l15;
#pragma unroll
        for (int nt = 0; nt < 2; ++nt){
#pragma unroll
          for (int r = 0; r < 4; ++r){
            int kg = kt*KVB + nt*16 + lhi*4 + r;
            if (kg > qg) st[nt][r] = -1e30f;
          }
        }
      }

      // ---- per-lane online softmax (q = l15) ----
      float pmax = fmaxf(fmaxf(fmaxf(st[0][0], st[0][1]), fmaxf(st[0][2], st[0][3])),
                         fmaxf(fmaxf(st[1][0], st[1][1]), fmaxf(st[1][2], st[1][3])));
      pmax = fmaxf(pmax, __shfl_xor(pmax, 16));
      pmax = fmaxf(pmax, __shfl_xor(pmax, 32));

      if (!__all(pmax - m <= 8.0f)){           // defer-max: rescale only on real growth
        float mn = fmaxf(m, pmax);
        float corr = exp2f(m - mn);
        m = mn;
        lsum *= corr;
        int srcb = (lane & 48) + ((lane >> 4) & 3)*4;
        float co[4];
#pragma unroll
        for (int r = 0; r < 4; ++r) co[r] = __shfl(corr, srcb + r);
#pragma unroll
        for (int i = 0; i < 8; ++i){
#pragma unroll
        for (int r = 0; r < 4; ++r) o[i][r] *= co[r];
        }
      }

      float p[2][4];
      float rs = 0.f;
#pragma unroll
      for (int nt = 0; nt < 2; ++nt){
#pragma unroll
        for (int r = 0; r < 4; ++r){
          float pp = exp2f(st[nt][r] - m);
          p[nt][r] = pp;
          rs += pp;
        }
      }
      rs += __shfl_xor(rs, 16);
      rs += __shfl_xor(rs, 32);
      lsum += rs;

      // ---- pack P hi/lo into u32 pairs (HW cvt_pk) ----
      unsigned ch[2][2], cl[2][2];
#pragma unroll
      for (int nt = 0; nt < 2; ++nt){
#pragma unroll
        for (int i = 0; i < 2; ++i){
          unsigned u = pkbf(p[nt][2*i], p[nt][2*i+1]);
          ch[nt][i] = u;
          float l0 = p[nt][2*i]   - asf(u << 16);
          float l1 = p[nt][2*i+1] - asf(u & 0xffff0000u);
          cl[nt][i] = pkbf(l0, l1);
        }
      }

      // ---- assemble PV A-frags via xor16 + xor32 shuffles ----
      // dest lane needs P[q=l15][kv=lhi*8+j]; element-verified mapping.
      bf16x8 pa[2];   // [0]=hi, [1]=lo
#pragma unroll
      for (int vH = 0; vH < 2; ++vH){
        unsigned c00 = vH ? cl[0][0] : ch[0][0];
        unsigned c01 = vH ? cl[0][1] : ch[0][1];
        unsigned c10 = vH ? cl[1][0] : ch[1][0];
        unsigned c11 = vH ? cl[1][1] : ch[1][1];
        unsigned pc00 = __shfl_xor((int)c00, 16);
        unsigned pc01 = __shfl_xor((int)c01, 16);
        unsigned pc10 = __shfl_xor((int)c10, 16);
        unsigned pc11 = __shfl_xor((int)c11, 16);
        bool odd = (lhi & 1);
        unsigned L00 = odd ? pc00 : c00,  L01 = odd ? pc01 : c01;
        unsigned H00 = odd ? c00  : pc00, H01 = odd ? c01  : pc01;
        unsigned L10 = odd ? pc10 : c10,  L11 = odd ? pc11 : c11;
        unsigned H10 = odd ? c10  : pc10, H11 = odd ? c11  : pc11;
        bool s1 = (lhi >> 1);
        unsigned K0 = s1 ? L10 : L00, K1 = s1 ? L11 : L01;
        unsigned K2 = s1 ? H10 : H00, K3 = s1 ? H11 : H01;
        unsigned S0 = s1 ? L00 : L10, S1v = s1 ? L01 : L11;
        unsigned S2 = s1 ? H00 : H10, S3 = s1 ? H01 : H11;
        unsigned R0 = __shfl_xor((int)S0, 32);
        unsigned R1 = __shfl_xor((int)S1v, 32);
        unsigned R2 = __shfl_xor((int)S2, 32);
        unsigned R3 = __shfl_xor((int)S3, 32);
        bool keep = (lhi == 0) || (lhi == 3);
        u32x4 F;
        F[0] = keep ? K0 : R0;  F[1] = keep ? K1 : R1;
        F[2] = keep ? K2 : R2;  F[3] = keep ? K3 : R3;
        pa[vH] = __builtin_bit_cast(bf16x8, F);
      }

      // ---- P·V (2-term: Ph·V + Pl·V) ----
      __builtin_amdgcn_s_setprio(1);
#pragma unroll
      for (int nt = 0; nt < 8; ++nt){
        int dr = nt*16 + l15;
        int vidx = dr*KVB + ((lhi ^ (dr & 3))*8);
        bf16x8 vb = *reinterpret_cast<const bf16x8*>(&lv[buf][vidx]);
        o[nt] = __builtin_amdgcn_mfma_f32_16x16x32_bf16(pa[0], vb, o[nt], 0, 0, 0);
        o[nt] = __builtin_amdgcn_mfma_f32_16x16x32_bf16(pa[1], vb, o[nt], 0, 0, 0);
      }
      __builtin_amdgcn_s_setprio(0);
    }

    __syncthreads();
  }

  // ---- epilogue: normalize (lsum lives per l15; O rows are lhi*4+r) ----
  float linv = 1.0f / lsum;
  int srcb = (lane & 48) + ((lane >> 4) & 3)*4;
  float inv[4];
#pragma unroll
  for (int r = 0; r < 4; ++r) inv[r] = __shfl(linv, srcb + r);
#pragma unroll
  for (int nt = 0; nt < 8; ++nt){
    int d = nt*16 + l15;
#pragma unroll
    for (int r = 0; r < 4; ++r){
      int sq = qb*QBLK + w*16 + (lane >> 4)*4 + r;
      out[((size_t)((b*S_ + sq)*H_ + h))*D_ + d] = o[nt][r] * inv[r];
    }
  }
}

extern "C" void kernel_launch(void* const* d_in, const int* in_sizes, int n_in,
                              void* d_out, int out_size, void* d_ws, size_t ws_size,
                              hipStream_t stream)
{
  const float* q     = (const float*)d_in[0];
  const float* k     = (const float*)d_in[1];
  const float* v     = (const float*)d_in[2];
  const float* scale = (const float*)d_in[4];   // d_in[3] = attention_mask (unused)
  float* out = (float*)d_out;
  (void)in_sizes; (void)n_in; (void)out_size; (void)ws_size;

  const size_t N = (size_t)B_ * S_ * H_ * D_;   // 8388608
  unsigned short* khi  = (unsigned short*)d_ws;        // 16 MiB
  unsigned short* vthi = khi + N;                      // 16 MiB

  prep_kernel<<<BH_*(S_/64), 256, 0, stream>>>(k, v, khi, vthi);
  attn_kernel<<<BH_*NQB, 256, 0, stream>>>(q, khi, vthi, scale, out);
}